// Round 3
// baseline (87.814 us; speedup 1.0000x reference)
//
#include <hip/hip_runtime.h>

#define NBR   24
#define CIN   16
#define COUT  64
#define LEN   8192
#define BATCH 16
#define KW    3

#define TL      256   // L positions per block tile
#define NC      8     // couts per wave
#define THREADS 512   // 8 waves: 8 cout-groups x 64 lanes (4 L each)

#define NW (COUT * CIN * KW)   // 3072 folded weights

__device__ __constant__ float d_coef[NBR] = {1,2,2,2,2,2, 1,2,2,2,2,2,
                                             1,2,2,2,2,2, 1,1,1,1,1,1};

// ---------------- prep: fold 24 branches into one conv ----------------
// Weff layout: [ci][c][t]  (so for fixed ci, a wave's 8 couts x 3 taps are
// 24 contiguous floats -> merged scalar loads)
__global__ void prep_fold(const float* __restrict__ W, const float* __restrict__ b,
                          float* __restrict__ Weff, float* __restrict__ beff) {
    int idx = blockIdx.x * blockDim.x + threadIdx.x;
    if (idx < NW) {
        int t  = idx % KW;
        int c  = (idx / KW) % COUT;
        int ci = idx / (KW * COUT);
        float s = 0.f;
#pragma unroll
        for (int k = 0; k < NBR; ++k)
            s += d_coef[k] * W[((k * COUT + c) * CIN + ci) * KW + t];
        Weff[idx] = s;
    } else if (idx < NW + COUT) {
        int c = idx - NW;
        float s = 0.f;
#pragma unroll
        for (int k = 0; k < NBR; ++k)
            s += d_coef[k] * b[k * COUT + c];
        beff[c] = s;
    }
}

// ---------------- main fused conv + bias + relu (fast path) ----------------
__global__ __launch_bounds__(THREADS) void conv_fused(
        const float* __restrict__ x, const float* __restrict__ Weff,
        const float* __restrict__ beff, float* __restrict__ out) {
    // +4 pad: row stride 260 floats = 1040 B (16B multiple) keeps every row's
    // float4 reads aligned; logical row is TL+2 (halo of 1 each side).
    __shared__ float xs[CIN][TL + 4];

    const int tid  = threadIdx.x;
    const int blk  = blockIdx.x;
    const int b    = blk >> 5;        // 32 tiles per batch (L/TL = 8192/256)
    const int tile = blk & 31;
    const int gl0  = tile * TL;

    const float* xb = x + (size_t)b * CIN * LEN;

    // stage x tile, shifted by -1: xs[ci][j] = x[b][ci][gl0 - 1 + j]
    for (int idx = tid; idx < CIN * (TL + 2); idx += THREADS) {
        int ci = idx / (TL + 2);
        int j  = idx - ci * (TL + 2);
        int gl = gl0 - 1 + j;
        xs[ci][j] = (gl >= 0 && gl < LEN) ? xb[ci * LEN + gl] : 0.f;
    }
    __syncthreads();

    // wave-uniform cout group -> weight/bias addresses become scalar loads
    const int wave = __builtin_amdgcn_readfirstlane(tid >> 6);
    const int lane = tid & 63;
    const int c0   = wave * NC;
    const int l0   = lane * 4;        // local L offset (float4-aligned in xs)

    float acc[NC][4];
#pragma unroll
    for (int c = 0; c < NC; ++c) {
        float bv = beff[c0 + c];
        acc[c][0] = bv; acc[c][1] = bv; acc[c][2] = bv; acc[c][3] = bv;
    }

    const float* wbase = Weff + c0 * KW;
#pragma unroll
    for (int ci = 0; ci < CIN; ++ci) {
        float xv[6];
        float4 xa  = *reinterpret_cast<const float4*>(&xs[ci][l0]);      // l-1..l+2
        float2 xb2 = *reinterpret_cast<const float2*>(&xs[ci][l0 + 4]);  // l+3..l+4
        xv[0] = xa.x; xv[1] = xa.y; xv[2] = xa.z; xv[3] = xa.w;
        xv[4] = xb2.x; xv[5] = xb2.y;
        const float* wci = wbase + ci * COUT * KW;
#pragma unroll
        for (int c = 0; c < NC; ++c) {
            float w0 = wci[c * KW + 0];
            float w1 = wci[c * KW + 1];
            float w2 = wci[c * KW + 2];
#pragma unroll
            for (int j = 0; j < 4; ++j)
                acc[c][j] = fmaf(w2, xv[j + 2],
                             fmaf(w1, xv[j + 1],
                              fmaf(w0, xv[j], acc[c][j])));
        }
    }

    float* ob = out + (size_t)b * COUT * LEN + gl0 + l0;
#pragma unroll
    for (int c = 0; c < NC; ++c) {
        float4 r;
        r.x = fmaxf(acc[c][0], 0.f);
        r.y = fmaxf(acc[c][1], 0.f);
        r.z = fmaxf(acc[c][2], 0.f);
        r.w = fmaxf(acc[c][3], 0.f);
        *reinterpret_cast<float4*>(ob + (size_t)(c0 + c) * LEN) = r;
    }
}

// ------------- fallback: no workspace, fold weights into LDS -------------
__global__ __launch_bounds__(THREADS) void conv_fused_fold(
        const float* __restrict__ x, const float* __restrict__ W,
        const float* __restrict__ bias, float* __restrict__ out) {
    __shared__ float xs[CIN][TL + 4];
    __shared__ float wf[NW];      // [ci][c][t]
    __shared__ float bf[COUT];

    const int tid  = threadIdx.x;
    const int blk  = blockIdx.x;
    const int b    = blk >> 5;
    const int tile = blk & 31;
    const int gl0  = tile * TL;

    // fold weights + bias into LDS
    for (int idx = tid; idx < NW; idx += THREADS) {
        int t  = idx % KW;
        int c  = (idx / KW) % COUT;
        int ci = idx / (KW * COUT);
        float s = 0.f;
#pragma unroll
        for (int k = 0; k < NBR; ++k)
            s += d_coef[k] * W[((k * COUT + c) * CIN + ci) * KW + t];
        wf[idx] = s;
    }
    if (tid < COUT) {
        float s = 0.f;
#pragma unroll
        for (int k = 0; k < NBR; ++k)
            s += d_coef[k] * bias[k * COUT + tid];
        bf[tid] = s;
    }

    const float* xb = x + (size_t)b * CIN * LEN;
    for (int idx = tid; idx < CIN * (TL + 2); idx += THREADS) {
        int ci = idx / (TL + 2);
        int j  = idx - ci * (TL + 2);
        int gl = gl0 - 1 + j;
        xs[ci][j] = (gl >= 0 && gl < LEN) ? xb[ci * LEN + gl] : 0.f;
    }
    __syncthreads();

    const int wave = __builtin_amdgcn_readfirstlane(tid >> 6);
    const int lane = tid & 63;
    const int c0   = wave * NC;
    const int l0   = lane * 4;

    float acc[NC][4];
#pragma unroll
    for (int c = 0; c < NC; ++c) {
        float bv = bf[c0 + c];
        acc[c][0] = bv; acc[c][1] = bv; acc[c][2] = bv; acc[c][3] = bv;
    }

#pragma unroll
    for (int ci = 0; ci < CIN; ++ci) {
        float xv[6];
        float4 xa  = *reinterpret_cast<const float4*>(&xs[ci][l0]);
        float2 xb2 = *reinterpret_cast<const float2*>(&xs[ci][l0 + 4]);
        xv[0] = xa.x; xv[1] = xa.y; xv[2] = xa.z; xv[3] = xa.w;
        xv[4] = xb2.x; xv[5] = xb2.y;
        const float* wci = &wf[(ci * COUT + c0) * KW];
#pragma unroll
        for (int c = 0; c < NC; ++c) {
            float w0 = wci[c * KW + 0];
            float w1 = wci[c * KW + 1];
            float w2 = wci[c * KW + 2];
#pragma unroll
            for (int j = 0; j < 4; ++j)
                acc[c][j] = fmaf(w2, xv[j + 2],
                             fmaf(w1, xv[j + 1],
                              fmaf(w0, xv[j], acc[c][j])));
        }
    }

    float* ob = out + (size_t)b * COUT * LEN + gl0 + l0;
#pragma unroll
    for (int c = 0; c < NC; ++c) {
        float4 r;
        r.x = fmaxf(acc[c][0], 0.f);
        r.y = fmaxf(acc[c][1], 0.f);
        r.z = fmaxf(acc[c][2], 0.f);
        r.w = fmaxf(acc[c][3], 0.f);
        *reinterpret_cast<float4*>(ob + (size_t)(c0 + c) * LEN) = r;
    }
}

extern "C" void kernel_launch(void* const* d_in, const int* in_sizes, int n_in,
                              void* d_out, int out_size, void* d_ws, size_t ws_size,
                              hipStream_t stream) {
    const float* x = (const float*)d_in[0];   // [16,16,8192]
    const float* W = (const float*)d_in[1];   // [24,64,16,3]
    const float* b = (const float*)d_in[2];   // [24,64]
    float* out = (float*)d_out;               // [16,64,8192]

    const size_t ws_need = (size_t)(NW + COUT) * sizeof(float);
    if (d_ws != nullptr && ws_size >= ws_need) {
        float* Weff = (float*)d_ws;           // 3072 floats, layout [ci][c][t]
        float* beff = Weff + NW;              // 64 floats
        const int prep_n = NW + COUT;         // 3136
        prep_fold<<<(prep_n + 255) / 256, 256, 0, stream>>>(W, b, Weff, beff);
        conv_fused<<<BATCH * (LEN / TL), THREADS, 0, stream>>>(x, Weff, beff, out);
    } else {
        conv_fused_fold<<<BATCH * (LEN / TL), THREADS, 0, stream>>>(x, W, b, out);
    }
}

// Round 7
// 85.723 us; speedup vs baseline: 1.0244x; 1.0244x over previous
//
#include <hip/hip_runtime.h>

#define NBR   24
#define CIN   16
#define COUT  64
#define LEN   8192
#define BATCH 16
#define KW    3

#define TL      256   // L positions per block tile
#define NC      8     // couts per wave
#define THREADS 512   // 8 waves: 8 cout-groups x 64 lanes (4 L each)

#define NW (COUT * CIN * KW)   // 3072 folded weights

typedef float v2f __attribute__((ext_vector_type(2)));

__device__ __constant__ float d_coef[NBR] = {1,2,2,2,2,2, 1,2,2,2,2,2,
                                             1,2,2,2,2,2, 1,1,1,1,1,1};

static __device__ __forceinline__ v2f fma2(v2f x, float s, v2f c) {
    v2f r;
    r.x = fmaf(x.x, s, c.x);
    r.y = fmaf(x.y, s, c.y);
    return r;
}

// ---------------- prep: fold 24 branches into one conv ----------------
// Threads enumerate W's native (c,ci,t) order -> perfectly coalesced reads
// of each 12 KB branch slab; the 12 KB scatter-write to Weff[ci][c][t] is
// negligible. Weff layout [ci][c][t] so a wave's 8 couts x 3 taps are 24
// contiguous floats -> merged s_load in the conv kernel.
__global__ void prep_fold(const float* __restrict__ W, const float* __restrict__ b,
                          float* __restrict__ Weff, float* __restrict__ beff) {
    int idx = blockIdx.x * blockDim.x + threadIdx.x;  // (c,ci,t) packed
    if (idx < NW) {
        float s = 0.f;
#pragma unroll
        for (int k = 0; k < NBR; ++k)
            s += d_coef[k] * W[k * NW + idx];
        int t  = idx % KW;
        int ci = (idx / KW) % CIN;
        int c  = idx / (KW * CIN);
        Weff[(ci * COUT + c) * KW + t] = s;
    } else if (idx < NW + COUT) {
        int c = idx - NW;
        float s = 0.f;
#pragma unroll
        for (int k = 0; k < NBR; ++k)
            s += d_coef[k] * b[k * COUT + c];
        beff[c] = s;
    }
}

// ---------------- main fused conv + bias + relu ----------------
__global__ __launch_bounds__(THREADS) void conv_fused(
        const float* __restrict__ x, const float* __restrict__ Weff,
        const float* __restrict__ beff, float* __restrict__ out) {
    // +4 pad: row stride 260 floats = 1040 B (16B multiple) keeps every row's
    // float4 reads aligned; logical row is TL+2 (halo of 1 each side).
    __shared__ float xs[CIN][TL + 4];

    const int tid  = threadIdx.x;
    const int blk  = blockIdx.x;
    const int b    = blk >> 5;        // 32 tiles per batch (L/TL = 8192/256)
    const int tile = blk & 31;
    const int gl0  = tile * TL;

    const float* xb = x + (size_t)b * CIN * LEN;

    // stage x tile, shifted by -1: xs[ci][j] = x[b][ci][gl0 - 1 + j]
    for (int idx = tid; idx < CIN * (TL + 2); idx += THREADS) {
        int ci = idx / (TL + 2);
        int j  = idx - ci * (TL + 2);
        int gl = gl0 - 1 + j;
        xs[ci][j] = (gl >= 0 && gl < LEN) ? xb[ci * LEN + gl] : 0.f;
    }
    __syncthreads();

    // wave-uniform cout group -> weight/bias addresses become scalar loads
    const int wave = __builtin_amdgcn_readfirstlane(tid >> 6);
    const int lane = tid & 63;
    const int c0   = wave * NC;
    const int l0   = lane * 4;        // local L offset (float4-aligned in xs)

    // packed accumulators: A[c][0] = outputs {l0,l0+1}, A[c][1] = {l0+2,l0+3}
    v2f A[NC][2];
#pragma unroll
    for (int c = 0; c < NC; ++c) {
        float bv = beff[c0 + c];
        A[c][0].x = bv; A[c][0].y = bv;
        A[c][1].x = bv; A[c][1].y = bv;
    }

    const float* wbase = Weff + c0 * KW;
#pragma unroll
    for (int ci = 0; ci < CIN; ++ci) {
        float4 xa  = *reinterpret_cast<const float4*>(&xs[ci][l0]);      // l-1..l+2
        float2 xb2 = *reinterpret_cast<const float2*>(&xs[ci][l0 + 4]);  // l+3..l+4
        v2f P01, P12, P23, P34, P45;   // sliding packed windows
        P01.x = xa.x;  P01.y = xa.y;
        P12.x = xa.y;  P12.y = xa.z;
        P23.x = xa.z;  P23.y = xa.w;
        P34.x = xa.w;  P34.y = xb2.x;
        P45.x = xb2.x; P45.y = xb2.y;
        const float* wci = wbase + ci * COUT * KW;
#pragma unroll
        for (int c = 0; c < NC; ++c) {
            float w0 = wci[c * KW + 0];
            float w1 = wci[c * KW + 1];
            float w2 = wci[c * KW + 2];
            A[c][0] = fma2(P01, w0, fma2(P12, w1, fma2(P23, w2, A[c][0])));
            A[c][1] = fma2(P23, w0, fma2(P34, w1, fma2(P45, w2, A[c][1])));
        }
    }

    float* ob = out + (size_t)b * COUT * LEN + gl0 + l0;
#pragma unroll
    for (int c = 0; c < NC; ++c) {
        float4 r;
        r.x = fmaxf(A[c][0].x, 0.f);
        r.y = fmaxf(A[c][0].y, 0.f);
        r.z = fmaxf(A[c][1].x, 0.f);
        r.w = fmaxf(A[c][1].y, 0.f);
        *reinterpret_cast<float4*>(ob + (size_t)(c0 + c) * LEN) = r;
    }
}

extern "C" void kernel_launch(void* const* d_in, const int* in_sizes, int n_in,
                              void* d_out, int out_size, void* d_ws, size_t ws_size,
                              hipStream_t stream) {
    const float* x = (const float*)d_in[0];   // [16,16,8192]
    const float* W = (const float*)d_in[1];   // [24,64,16,3]
    const float* b = (const float*)d_in[2];   // [24,64]
    float* out = (float*)d_out;               // [16,64,8192]

    float* Weff = (float*)d_ws;               // 3072 floats, layout [ci][c][t]
    float* beff = Weff + NW;                  // 64 floats
    const int prep_n = NW + COUT;             // 3136
    prep_fold<<<(prep_n + 255) / 256, 256, 0, stream>>>(W, b, Weff, beff);
    conv_fused<<<BATCH * (LEN / TL), THREADS, 0, stream>>>(x, Weff, beff, out);
}

// Round 8
// 84.104 us; speedup vs baseline: 1.0441x; 1.0192x over previous
//
#include <hip/hip_runtime.h>

#define NBR   24
#define CIN   16
#define COUT  64
#define LEN   8192
#define BATCH 16
#define KW    3

#define TL      256   // L positions per block tile
#define NC      8     // couts per wave
#define THREADS 512   // 8 waves: 8 cout-groups x 64 lanes (4 L each)

#define NW (COUT * CIN * KW)   // 3072 folded weights

typedef float v2f __attribute__((ext_vector_type(2)));

__device__ __constant__ float d_coef[NBR] = {1,2,2,2,2,2, 1,2,2,2,2,2,
                                             1,2,2,2,2,2, 1,1,1,1,1,1};

static __device__ __forceinline__ v2f fma2(v2f x, float s, v2f c) {
    v2f r;
    r.x = fmaf(x.x, s, c.x);
    r.y = fmaf(x.y, s, c.y);
    return r;
}

// Single fused kernel: per-block weight fold (LDS) + conv + bias + relu.
// Eliminates the separate prep dispatch; the 288 KB/block W re-read is
// L2-resident (W is 294 KB total) and hides under the x staging loads.
__global__ __launch_bounds__(THREADS) void conv_all(
        const float* __restrict__ x, const float* __restrict__ W,
        const float* __restrict__ bias, float* __restrict__ out) {
    // xs: +4 pad keeps row stride 260 floats = 1040 B (16B multiple) so every
    // lane's float4 read is aligned; logical row is TL+2 (halo 1 each side).
    __shared__ float xs[CIN][TL + 4];
    __shared__ float wf[NW];          // folded weights, layout [ci][c][t]
    __shared__ float bf[COUT];        // folded bias

    const int tid  = threadIdx.x;
    const int blk  = blockIdx.x;
    const int b    = blk >> 5;        // 32 tiles per batch (L/TL = 8192/256)
    const int tile = blk & 31;
    const int gl0  = tile * TL;

    // ---- fold weights: threads enumerate W's native (c,ci,t) order so the
    // 24 branch reads are fully coalesced; scatter-write into wf[ci][c][t].
#pragma unroll
    for (int it = 0; it < NW / THREADS; ++it) {       // 6 iters
        int idx = it * THREADS + tid;
        float s = 0.f;
#pragma unroll
        for (int k = 0; k < NBR; ++k)
            s += d_coef[k] * W[k * NW + idx];
        int t  = idx % KW;
        int ci = (idx / KW) % CIN;
        int c  = idx / (KW * CIN);
        wf[(ci * COUT + c) * KW + t] = s;
    }
    if (tid < COUT) {
        float s = 0.f;
#pragma unroll
        for (int k = 0; k < NBR; ++k)
            s += d_coef[k] * bias[k * COUT + tid];
        bf[tid] = s;
    }

    // ---- stage x tile, shifted by -1: xs[ci][j] = x[b][ci][gl0 - 1 + j]
    const float* xb = x + (size_t)b * CIN * LEN;
    for (int idx = tid; idx < CIN * (TL + 2); idx += THREADS) {
        int ci = idx / (TL + 2);
        int j  = idx - ci * (TL + 2);
        int gl = gl0 - 1 + j;
        xs[ci][j] = (gl >= 0 && gl < LEN) ? xb[ci * LEN + gl] : 0.f;
    }
    __syncthreads();

    // wave-uniform cout group
    const int wave = __builtin_amdgcn_readfirstlane(tid >> 6);
    const int lane = tid & 63;
    const int c0   = wave * NC;
    const int l0   = lane * 4;        // local L offset (float4-aligned in xs)

    // packed accumulators: A[c][0] = outputs {l0,l0+1}, A[c][1] = {l0+2,l0+3}
    v2f A[NC][2];
#pragma unroll
    for (int c = 0; c < NC; ++c) {
        float bv = bf[c0 + c];
        A[c][0].x = bv; A[c][0].y = bv;
        A[c][1].x = bv; A[c][1].y = bv;
    }

#pragma unroll
    for (int ci = 0; ci < CIN; ++ci) {
        float4 xa  = *reinterpret_cast<const float4*>(&xs[ci][l0]);      // l-1..l+2
        float2 xb2 = *reinterpret_cast<const float2*>(&xs[ci][l0 + 4]);  // l+3..l+4
        v2f P01, P12, P23, P34, P45;   // sliding packed windows
        P01.x = xa.x;  P01.y = xa.y;
        P12.x = xa.y;  P12.y = xa.z;
        P23.x = xa.z;  P23.y = xa.w;
        P34.x = xa.w;  P34.y = xb2.x;
        P45.x = xb2.x; P45.y = xb2.y;

        // 24 contiguous folded weights for this wave's 8 couts:
        // byte offset = ci*768 + wave*96 -> 16B aligned; 6 x ds_read_b128
        const float4* wq = reinterpret_cast<const float4*>(&wf[(ci * COUT + c0) * KW]);
        float4 wv0 = wq[0], wv1 = wq[1], wv2 = wq[2];
        float4 wv3 = wq[3], wv4 = wq[4], wv5 = wq[5];
        float wreg[24] = {wv0.x, wv0.y, wv0.z, wv0.w,
                          wv1.x, wv1.y, wv1.z, wv1.w,
                          wv2.x, wv2.y, wv2.z, wv2.w,
                          wv3.x, wv3.y, wv3.z, wv3.w,
                          wv4.x, wv4.y, wv4.z, wv4.w,
                          wv5.x, wv5.y, wv5.z, wv5.w};
#pragma unroll
        for (int c = 0; c < NC; ++c) {
            float w0 = wreg[c * KW + 0];
            float w1 = wreg[c * KW + 1];
            float w2 = wreg[c * KW + 2];
            A[c][0] = fma2(P01, w0, fma2(P12, w1, fma2(P23, w2, A[c][0])));
            A[c][1] = fma2(P23, w0, fma2(P34, w1, fma2(P45, w2, A[c][1])));
        }
    }

    float* ob = out + (size_t)b * COUT * LEN + gl0 + l0;
#pragma unroll
    for (int c = 0; c < NC; ++c) {
        float4 r;
        r.x = fmaxf(A[c][0].x, 0.f);
        r.y = fmaxf(A[c][0].y, 0.f);
        r.z = fmaxf(A[c][1].x, 0.f);
        r.w = fmaxf(A[c][1].y, 0.f);
        *reinterpret_cast<float4*>(ob + (size_t)(c0 + c) * LEN) = r;
    }
}

extern "C" void kernel_launch(void* const* d_in, const int* in_sizes, int n_in,
                              void* d_out, int out_size, void* d_ws, size_t ws_size,
                              hipStream_t stream) {
    const float* x = (const float*)d_in[0];   // [16,16,8192]
    const float* W = (const float*)d_in[1];   // [24,64,16,3]
    const float* b = (const float*)d_in[2];   // [24,64]
    float* out = (float*)d_out;               // [16,64,8192]

    conv_all<<<BATCH * (LEN / TL), THREADS, 0, stream>>>(x, W, b, out);
}